// Round 1
// baseline (842.639 us; speedup 1.0000x reference)
//
#include <hip/hip_runtime.h>
#include <math.h>

#define TPB 256

namespace {

constexpr int IN_FEAT = 512;
constexpr int HID = 16;

// ---- edge dtype detect: int64 (all high words zero) vs int32 ----
__global__ void k_detect(const int* __restrict__ ei32, int* __restrict__ flag) {
  __shared__ int red[TPB];
  int t = threadIdx.x;
  int v = 0;
  for (int i = t; i < 2048; i += TPB) v |= ei32[2 * i + 1];
  red[t] = v;
  __syncthreads();
  for (int s = TPB / 2; s > 0; s >>= 1) {
    if (t < s) red[t] |= red[t + s];
    __syncthreads();
  }
  if (t == 0) *flag = (red[0] == 0) ? 1 : 0;  // 1 => int64 layout
}

__global__ void k_deg_init(float* __restrict__ deg, int n) {
  int i = blockIdx.x * TPB + threadIdx.x;
  if (i < n) deg[i] = 1.0f;  // self-loop
}

__global__ void k_deg_accum(const int* __restrict__ ei32, const long long* __restrict__ ei64,
                            const int* __restrict__ flag, float* __restrict__ deg, int E) {
  int e = blockIdx.x * TPB + threadIdx.x;
  if (e >= E) return;
  int d = (*flag) ? (int)ei64[(long long)E + e] : ei32[(long long)E + e];
  atomicAdd(&deg[d], 1.0f);
}

__global__ void k_rsqrt(float* __restrict__ deg, int n) {
  int i = blockIdx.x * TPB + threadIdx.x;
  if (i < n) deg[i] = rsqrtf(deg[i]);
}

// ---- layer1 GEMM: hs1 = (x @ W1) * dinv[row];  t1 = hs1 (self-loop init) ----
// 16-row tiles, one output/thread (16r x 16c), LDS xor-swizzled 16B chunks.
__global__ __launch_bounds__(TPB) void k_gemm1(const float* __restrict__ x,
                                               const float* __restrict__ W1,
                                               const float* __restrict__ dinv,
                                               float* __restrict__ hs1,
                                               float* __restrict__ t1, int n) {
  __shared__ float Wt[HID * IN_FEAT];  // [c][k], chunk (k>>2) xor (c&7)
  __shared__ float xs[16 * IN_FEAT];   // [r][k], chunk (k>>2) xor (r&7)
  int t = threadIdx.x;
  for (int i = t; i < IN_FEAT * HID; i += TPB) {
    int k = i >> 4, c = i & 15;
    int pk = (k >> 2) ^ (c & 7);
    Wt[c * IN_FEAT + (pk << 2) + (k & 3)] = W1[i];
  }
  int c = t >> 4, r = t & 15;
  int xsw = r & 7, wsw = c & 7;
  int ntiles = (n + 15) >> 4;
  for (int tile = blockIdx.x; tile < ntiles; tile += gridDim.x) {
    int r0 = tile << 4;
    for (int i = t; i < 16 * (IN_FEAT / 4); i += TPB) {
      int rr = i >> 7, kk = i & 127;
      int row = r0 + rr;
      if (row > n - 1) row = n - 1;
      float4 v = ((const float4*)x)[(long long)row * (IN_FEAT / 4) + kk];
      *(float4*)&xs[rr * IN_FEAT + ((kk ^ (rr & 7)) << 2)] = v;
    }
    __syncthreads();
    float acc = 0.f;
#pragma unroll 8
    for (int kk = 0; kk < IN_FEAT / 4; kk++) {
      float4 xv = *(const float4*)&xs[r * IN_FEAT + ((kk ^ xsw) << 2)];
      float4 wv = *(const float4*)&Wt[c * IN_FEAT + ((kk ^ wsw) << 2)];
      acc = fmaf(xv.x, wv.x, acc);
      acc = fmaf(xv.y, wv.y, acc);
      acc = fmaf(xv.z, wv.z, acc);
      acc = fmaf(xv.w, wv.w, acc);
    }
    int row = r0 + r;
    if (row < n) {
      float val = acc * dinv[row];
      hs1[(long long)row * HID + c] = val;
      t1[(long long)row * HID + c] = val;
    }
    __syncthreads();
  }
}

// ---- edge scatter layer1: t1[dst][f] += hs1[src][f], 16 lanes/edge ----
__global__ void k_scatter1(const int* __restrict__ ei32, const long long* __restrict__ ei64,
                           const int* __restrict__ flag, const float* __restrict__ hs1,
                           float* __restrict__ t1, int E) {
  long long gid = (long long)blockIdx.x * TPB + threadIdx.x;
  long long e = gid >> 4;
  if (e >= E) return;
  int f = (int)(gid & 15);
  int s, d;
  if (*flag) {
    s = (int)ei64[e];
    d = (int)ei64[E + e];
  } else {
    s = ei32[e];
    d = ei32[(long long)E + e];
  }
  atomicAdd(&t1[(long long)d * HID + f], hs1[(long long)s * HID + f]);
}

// ---- layer1 epilogue + layer2 GEMM: h1 = relu(dinv*t1 + b1); hs2 = (h1@W2)*dinv ----
__global__ void k_layer2(const float* __restrict__ t1, const float* __restrict__ dinv,
                         const float* __restrict__ b1, const float* __restrict__ W2,
                         float* __restrict__ hs2, float* __restrict__ t2, int n) {
  int i = blockIdx.x * TPB + threadIdx.x;
  if (i >= n) return;
  float di = dinv[i];
  float h[16];
  const float4* tp = (const float4*)(t1 + (long long)i * 16);
#pragma unroll
  for (int q = 0; q < 4; q++) {
    float4 v = tp[q];
    float4 b = ((const float4*)b1)[q];
    h[4 * q + 0] = fmaxf(fmaf(di, v.x, b.x), 0.f);
    h[4 * q + 1] = fmaxf(fmaf(di, v.y, b.y), 0.f);
    h[4 * q + 2] = fmaxf(fmaf(di, v.z, b.z), 0.f);
    h[4 * q + 3] = fmaxf(fmaf(di, v.w, b.w), 0.f);
  }
  float o[8];
#pragma unroll
  for (int j = 0; j < 7; j++) {
    float s = 0.f;
#pragma unroll
    for (int cc = 0; cc < 16; cc++) s = fmaf(h[cc], W2[cc * 7 + j], s);
    o[j] = s * di;
  }
  o[7] = 0.f;
  float4* hp = (float4*)(hs2 + (long long)i * 8);
  float4* qp = (float4*)(t2 + (long long)i * 8);
  float4 lo = make_float4(o[0], o[1], o[2], o[3]);
  float4 hi = make_float4(o[4], o[5], o[6], o[7]);
  hp[0] = lo; hp[1] = hi;
  qp[0] = lo; qp[1] = hi;
}

// ---- edge scatter layer2: t2[dst][f] += hs2[src][f], 8 lanes/edge (f<7 active) ----
__global__ void k_scatter2(const int* __restrict__ ei32, const long long* __restrict__ ei64,
                           const int* __restrict__ flag, const float* __restrict__ hs2,
                           float* __restrict__ t2, int E) {
  long long gid = (long long)blockIdx.x * TPB + threadIdx.x;
  long long e = gid >> 3;
  if (e >= E) return;
  int f = (int)(gid & 7);
  if (f == 7) return;
  int s, d;
  if (*flag) {
    s = (int)ei64[e];
    d = (int)ei64[E + e];
  } else {
    s = ei32[e];
    d = ei32[(long long)E + e];
  }
  atomicAdd(&t2[(long long)d * 8 + f], hs2[(long long)s * 8 + f]);
}

// ---- finalize: logits = dinv*t2 + b2; log_softmax ----
__global__ void k_final(const float* __restrict__ t2, const float* __restrict__ dinv,
                        const float* __restrict__ b2, float* __restrict__ out, int n) {
  int i = blockIdx.x * TPB + threadIdx.x;
  if (i >= n) return;
  float di = dinv[i];
  float v[7];
  float m = -1e30f;
#pragma unroll
  for (int j = 0; j < 7; j++) {
    v[j] = fmaf(di, t2[(long long)i * 8 + j], b2[j]);
    m = fmaxf(m, v[j]);
  }
  float s = 0.f;
#pragma unroll
  for (int j = 0; j < 7; j++) s += expf(v[j] - m);
  float lse = m + logf(s);
#pragma unroll
  for (int j = 0; j < 7; j++) out[(long long)i * 7 + j] = v[j] - lse;
}

}  // namespace

extern "C" void kernel_launch(void* const* d_in, const int* in_sizes, int n_in,
                              void* d_out, int out_size, void* d_ws, size_t ws_size,
                              hipStream_t stream) {
  const float* x = (const float*)d_in[0];
  const int* ei32 = (const int*)d_in[1];
  const long long* ei64 = (const long long*)d_in[1];
  const float* W1 = (const float*)d_in[2];
  const float* b1 = (const float*)d_in[3];
  const float* W2 = (const float*)d_in[4];
  const float* b2 = (const float*)d_in[5];
  float* out = (float*)d_out;

  int n = in_sizes[0] / IN_FEAT;  // 100000
  int E = in_sizes[1] / 2;        // 3200000

  float* ws = (float*)d_ws;
  int* flag = (int*)d_ws;
  float* dinv = ws + 64;
  float* hs1 = dinv + n;
  float* t1 = hs1 + (long long)n * HID;
  float* hs2 = t1 + (long long)n * HID;
  float* t2 = hs2 + (long long)n * 8;

  int nb_n = (n + TPB - 1) / TPB;
  int nb_e = (E + TPB - 1) / TPB;
  long long w1 = (long long)E * 16, w2 = (long long)E * 8;
  int nb_s1 = (int)((w1 + TPB - 1) / TPB);
  int nb_s2 = (int)((w2 + TPB - 1) / TPB);

  hipLaunchKernelGGL(k_detect, dim3(1), dim3(TPB), 0, stream, ei32, flag);
  hipLaunchKernelGGL(k_deg_init, dim3(nb_n), dim3(TPB), 0, stream, dinv, n);
  hipLaunchKernelGGL(k_deg_accum, dim3(nb_e), dim3(TPB), 0, stream, ei32, ei64, flag, dinv, E);
  hipLaunchKernelGGL(k_rsqrt, dim3(nb_n), dim3(TPB), 0, stream, dinv, n);
  hipLaunchKernelGGL(k_gemm1, dim3(1024), dim3(TPB), 0, stream, x, W1, dinv, hs1, t1, n);
  hipLaunchKernelGGL(k_scatter1, dim3(nb_s1), dim3(TPB), 0, stream, ei32, ei64, flag, hs1, t1, E);
  hipLaunchKernelGGL(k_layer2, dim3(nb_n), dim3(TPB), 0, stream, t1, dinv, b1, W2, hs2, t2, n);
  hipLaunchKernelGGL(k_scatter2, dim3(nb_s2), dim3(TPB), 0, stream, ei32, ei64, flag, hs2, t2, E);
  hipLaunchKernelGGL(k_final, dim3(nb_n), dim3(TPB), 0, stream, t2, dinv, b2, out, n);
}